// Round 16
// baseline (264.281 us; speedup 1.0000x reference)
//
#include <hip/hip_runtime.h>
#include <hip/hip_fp16.h>

#define BB 4096
#define CC 512
#define TT 4096
#define NN 1023
#define NL 1024

// ===================== pre-kernels (write d_ws) =====================
// MIRRORED layout: traversal tracks p = 2p + signbit(m).  Mirrored slot j at
// depth d holds actual node n = 3*2^d - 2 - j.  Children of mirrored slot p sit
// at mirrored slots {2p (sign=0 -> actual right child), 2p+1 (sign=1 -> left)}.

__device__ __forceinline__ unsigned pack_node(float th, int o) {
    // (ord*128) in high 16 bits = byte offset into a 64-sample xs row; f16(thr) low.
    return ((unsigned)o << 23) | (unsigned)__half_as_ushort(__float2half(th));
}

// pk_lo[t][j] j=0..127 : mirrored slots, depths 0..6 (512B/tree); slot 0 = 0
// g7[t][k]  k=0..63   : depth-7 pair for mirrored depth-6 slot 64+k  = {n(254-2k), n(253-2k)}
// g8[t][k]  k=0..127  : depth-8 pair for mirrored depth-7 slot 128+k = {n(510-2k), n(509-2k)}
// tails[t][i] i=0..255: depth-9 pair + leaf weights for mirrored depth-8 slot 256+i:
//   {n(1022-2i), n(1021-2i), w01={lo:w[1023-4i],hi:w[1022-4i]}, w23={lo:w[1021-4i],hi:w[1020-4i]}}
__global__ __launch_bounds__(256)
void pack_trees(const float* __restrict__ thr, const int* __restrict__ ord,
                const float* __restrict__ wts, unsigned* __restrict__ pk_lo,
                uint2* __restrict__ g7, uint2* __restrict__ g8,
                uint4* __restrict__ tails) {
    int t = blockIdx.x, tid = threadIdx.x;
    const float* tr = thr + (size_t)t * NN;
    const int*   oo = ord + (size_t)t * NN;
    if (tid < 128) {
        unsigned* plo = pk_lo + ((size_t)t << 7);
        if (tid == 0) plo[0] = 0u;
        else {
            int d = 31 - __clz(tid);
            int n = 3 * (1 << d) - 2 - tid;
            plo[tid] = pack_node(tr[n], oo[n]);
        }
    }
    if (tid < 64) {
        int k = tid;
        g7[((size_t)t << 6) + k] =
            make_uint2(pack_node(tr[254 - 2 * k], oo[254 - 2 * k]),
                       pack_node(tr[253 - 2 * k], oo[253 - 2 * k]));
    }
    if (tid < 128) {
        int k = tid;
        g8[((size_t)t << 7) + k] =
            make_uint2(pack_node(tr[510 - 2 * k], oo[510 - 2 * k]),
                       pack_node(tr[509 - 2 * k], oo[509 - 2 * k]));
    }
    {
        int i = tid;
        unsigned A = pack_node(tr[1022 - 2 * i], oo[1022 - 2 * i]);
        unsigned B = pack_node(tr[1021 - 2 * i], oo[1021 - 2 * i]);
        float4 w4 = *(const float4*)(wts + ((size_t)t << 10) + (1020 - 4 * i));
        unsigned w01 = (unsigned)__half_as_ushort(__float2half(w4.w)) |
                       ((unsigned)__half_as_ushort(__float2half(w4.z)) << 16);
        unsigned w23 = (unsigned)__half_as_ushort(__float2half(w4.y)) |
                       ((unsigned)__half_as_ushort(__float2half(w4.x)) << 16);
        tails[((size_t)t << 8) + i] = make_uint4(A, B, w01, w23);
    }
}

// xt16[c*4096 + b] = f16bits(x[b][c])
__global__ __launch_bounds__(256)
void pack_x16(const float* __restrict__ x, unsigned short* __restrict__ xt16) {
    __shared__ float tile[64][65];
    int tx = threadIdx.x & 63, ty = threadIdx.x >> 6;   // 64 x 4
    int b0 = blockIdx.x * 64;
    int c0 = blockIdx.y * 64;
    #pragma unroll
    for (int i = 0; i < 16; ++i) {
        int rr = i * 4 + ty;
        tile[rr][tx] = x[(size_t)(b0 + rr) * CC + c0 + tx];
    }
    __syncthreads();
    #pragma unroll
    for (int i = 0; i < 16; ++i) {
        int cr = i * 4 + ty;
        xt16[(size_t)(c0 + cr) * BB + b0 + tx] =
            __half_as_ushort(__float2half(tile[tx][cr]));
    }
}

// ===================== packed helpers =====================
typedef unsigned short u16x2 __attribute__((ext_vector_type(2)));

static __device__ __forceinline__ unsigned psub_f16x2(unsigned a, unsigned b) {
    __half2 ah, bh;
    __builtin_memcpy(&ah, &a, 4);
    __builtin_memcpy(&bh, &b, 4);
    __half2 r = ah - bh;
    unsigned u; __builtin_memcpy(&u, &r, 4); return u;
}
static __device__ __forceinline__ unsigned pmin_u16x2(unsigned a, unsigned b) {
    u16x2 av, bv;
    __builtin_memcpy(&av, &a, 4);
    __builtin_memcpy(&bv, &b, 4);
    u16x2 m = __builtin_elementwise_min(av, bv);
    unsigned u; __builtin_memcpy(&u, &m, 4); return u;
}
static __device__ __forceinline__ float f16lo(unsigned u) {
    return __half2float(__ushort_as_half((unsigned short)(u & 0xffffu)));
}
static __device__ __forceinline__ float f16hi(unsigned u) {
    return __half2float(__ushort_as_half((unsigned short)(u >> 16)));
}

// ===================== main kernel =====================
// grid 2048, XCD-swizzled. 1024 threads = 16 waves (4/SIMD), lane = sample,
// 8 chains/thread, single group of 128 trees. Depths 0..6 staged (512B/tree).
// Levels 6,7 via 8B g7/g8, level 8/9 + weights via 16B tails (L2).
// Output staged in LDS res tile, then written coalesced (load-bearing! round-15
// showed direct scattered 32B stores cost 3.4x WRITE_SIZE and 2.5x time).
// LDS (160 KiB): xs16 u16[512][64] 64K @0 | trees 64K @64K | res f32[64][128] 32K @128K
#define LDS_BYTES 163840

typedef __attribute__((address_space(1))) const void gv_t;
typedef __attribute__((address_space(3))) void lv_t;

__global__ __launch_bounds__(1024, 1)
void rhf_main(const unsigned* __restrict__ pk_lo, const uint2* __restrict__ g7g,
              const uint2* __restrict__ g8g, const uint4* __restrict__ tails,
              const unsigned short* __restrict__ xt16, float* __restrict__ out) {
    extern __shared__ char smem[];
    const char* xsb = (const char*)smem;            // xs16 byte base
    unsigned*   trl = (unsigned*)(smem + 65536);
    float*      res = (float*)(smem + 131072);

    const int tid  = threadIdx.x;
    const int lane = tid & 63;
    const int wv   = tid >> 6;          // 0..15
    const int bi   = blockIdx.x;
    const int tb    = ((bi & 7) << 2) + ((bi >> 3) >> 6);   // 0..31
    const int panel = (bi >> 3) & 63;                       // 0..63
    const int lane2 = lane << 1;

    // ---- per-wave tree DMA: 8 trees x 512B = 4KB ----
    {
        const char* s = (const char*)pk_lo + ((size_t)(tb * 128 + wv * 8) << 9) + lane * 16;
        char* d = (char*)trl + wv * 4096 + lane * 16;
        #pragma unroll
        for (int q = 0; q < 4; ++q)
            __builtin_amdgcn_global_load_lds((gv_t*)(s + q * 1024),
                                             (lv_t*)(d + q * 1024), 16, 0, 0);
    }

    // ---- stage xs16 via global_load_lds (per-lane src, linear LDS dest) ----
    {
        const unsigned short* src = xt16 + (size_t)panel * 64;
        #pragma unroll
        for (int k = 0; k < 4; ++k) {
            int i4 = k * 1024 + tid;          // 16B unit index
            int c  = i4 >> 3;
            int o8 = (i4 & 7) << 3;           // u16 offset in row
            __builtin_amdgcn_global_load_lds((gv_t*)(src + (size_t)c * BB + o8),
                                             (lv_t*)((char*)smem + ((size_t)i4 << 4)),
                                             16, 0, 0);
        }
    }
    __syncthreads();   // all DMA drained; xs16 + trees visible

    const int t0 = tb * 128 + wv * 8;
    const unsigned* pkw = trl + wv * 1024;

    // packed eval for chains (a,b): sign bits out as bools (v_cmp masks)
    auto evalpair = [&](unsigned nd_a, unsigned nd_b, unsigned& amin,
                        bool& s_a, bool& s_b) {
        unsigned thv2 = __builtin_amdgcn_perm(nd_b, nd_a, 0x05040100u);
        unsigned fa = *(const unsigned short*)(xsb + (nd_a >> 16) + lane2);
        unsigned fb = *(const unsigned short*)(xsb + (nd_b >> 16) + lane2);
        unsigned feat2 = fa | (fb << 16);
        unsigned mb = psub_f16x2(feat2, thv2);
        amin = pmin_u16x2(amin, mb & 0x7fff7fffu);
        s_a = (short)(mb & 0xffffu) < 0;
        s_b = (int)mb < 0;
    };

    unsigned amin[4];
    unsigned sl[8];
    unsigned nd[8];
    bool     s[8];
    #pragma unroll
    for (int p = 0; p < 4; ++p) amin[p] = 0x7c007c00u;
    #pragma unroll
    for (int c = 0; c < 8; ++c) { sl[c] = 1; nd[c] = pkw[c * 128 + 1]; }

    // ---- levels 0..5 (children from LDS; select .y on sign) ----
    #pragma unroll
    for (int d = 0; d < 6; ++d) {
        uint2 ch[8];
        #pragma unroll
        for (int c = 0; c < 8; ++c)
            ch[c] = *(const uint2*)(pkw + c * 128 + 2 * sl[c]);
        #pragma unroll
        for (int p = 0; p < 4; ++p)
            evalpair(nd[2 * p], nd[2 * p + 1], amin[p], s[2 * p], s[2 * p + 1]);
        #pragma unroll
        for (int c = 0; c < 8; ++c) {
            sl[c] = 2 * sl[c] + (s[c] ? 1u : 0u);
            nd[c] = s[c] ? ch[c].y : ch[c].x;
        }
    }

    // ---- level 6: depth-7 pairs from g7 (8B, L2) ----
    {
        uint2 q[8];
        #pragma unroll
        for (int c = 0; c < 8; ++c)
            q[c] = g7g[((size_t)(t0 + c) << 6) + (sl[c] - 64)];
        #pragma unroll
        for (int p = 0; p < 4; ++p)
            evalpair(nd[2 * p], nd[2 * p + 1], amin[p], s[2 * p], s[2 * p + 1]);
        #pragma unroll
        for (int c = 0; c < 8; ++c) {
            sl[c] = 2 * sl[c] + (s[c] ? 1u : 0u);
            nd[c] = s[c] ? q[c].y : q[c].x;
        }
    }

    // ---- level 7: depth-8 pairs from g8 (8B, L2) ----
    {
        uint2 q[8];
        #pragma unroll
        for (int c = 0; c < 8; ++c)
            q[c] = g8g[((size_t)(t0 + c) << 7) + (sl[c] - 128)];
        #pragma unroll
        for (int p = 0; p < 4; ++p)
            evalpair(nd[2 * p], nd[2 * p + 1], amin[p], s[2 * p], s[2 * p + 1]);
        #pragma unroll
        for (int c = 0; c < 8; ++c) {
            sl[c] = 2 * sl[c] + (s[c] ? 1u : 0u);
            nd[c] = s[c] ? q[c].y : q[c].x;
        }
    }

    // ---- level 8: tails (16B, L2) -> depth-9 node + weight word ----
    unsigned wsel[8];
    {
        uint4 e[8];
        #pragma unroll
        for (int c = 0; c < 8; ++c)
            e[c] = tails[((size_t)(t0 + c) << 8) + (sl[c] - 256)];
        #pragma unroll
        for (int p = 0; p < 4; ++p)
            evalpair(nd[2 * p], nd[2 * p + 1], amin[p], s[2 * p], s[2 * p + 1]);
        #pragma unroll
        for (int c = 0; c < 8; ++c) {
            nd[c]   = s[c] ? e[c].y : e[c].x;
            wsel[c] = s[c] ? e[c].w : e[c].z;
        }
    }

    // ---- level 9 + weight, write res tile (swizzled, 2-way free) ----
    {
        #pragma unroll
        for (int p = 0; p < 4; ++p)
            evalpair(nd[2 * p], nd[2 * p + 1], amin[p], s[2 * p], s[2 * p + 1]);
        #pragma unroll
        for (int c = 0; c < 8; ++c) {
            unsigned short wb = (unsigned short)(s[c] ? (wsel[c] >> 16) : (wsel[c] & 0xffffu));
            float am = (c & 1) ? f16hi(amin[c >> 1]) : f16lo(amin[c >> 1]);
            float o  = am * __half2float(__ushort_as_half(wb));
            int col = wv * 8 + c;
            res[(lane << 7) + ((col + lane) & 127)] = o;
        }
    }
    __syncthreads();

    // ---- coalesced output ----
    float* obase = out + (size_t)(tb * 128);
    #pragma unroll
    for (int k = 0; k < 8; ++k) {
        int idx = k * 1024 + tid;
        int rr = idx >> 7, cc = idx & 127;
        float v = res[(rr << 7) + ((cc + rr) & 127)];
        obase[((size_t)panel * 64 + rr) * TT + cc] = v;
    }
}

// ===================== fallback (proven 541us path) =====================
#define F_SP 32
#define F_TG 16
#define F_GROUPS 8
#define F_TPB (F_TG * F_GROUPS)
#define F_NPANELS (BB / F_SP)
#define F_LDS 147456

__global__ __launch_bounds__(512, 1)
void rhf_fallback(const float* __restrict__ x, const float* __restrict__ thr_g,
                  const int* __restrict__ ord_g, const float* __restrict__ wts,
                  float* __restrict__ out) {
    extern __shared__ char smem[];
    float*        xs  = (float*)(smem);
    unsigned int* pk  = (unsigned int*)(smem + 65536);
    float*        res = (float*)(smem + 131072);
    const int tid = threadIdx.x, s = tid & 31, slot = tid >> 5;
    const int panel = blockIdx.x & (F_NPANELS - 1), tb = blockIdx.x >> 7;
    const float* xbase = x + (size_t)panel * F_SP * CC;
    #pragma unroll
    for (int k = 0; k < (F_SP * CC) / 512; ++k) {
        int idx = k * 512 + tid, r = idx >> 9, c = idx & 511;
        xs[(c << 5) + r] = xbase[r * CC + c];
    }
    float4 pthr[8]; int4 pord[8]; float tthr[3]; int tord[3];
    auto prefetch = [&](int g) {
        const size_t base = (size_t)(tb * F_TPB + g * F_TG + slot) * NN;
        #pragma unroll
        for (int k = 0; k < 8; ++k) {
            int j = k * 128 + 4 * s;
            if (j < 1020) { pthr[k] = *(const float4*)(thr_g + base + j);
                            pord[k] = *(const int4*)(ord_g + base + j); }
            else { tthr[0]=thr_g[base+1020]; tord[0]=ord_g[base+1020];
                   tthr[1]=thr_g[base+1021]; tord[1]=ord_g[base+1021];
                   tthr[2]=thr_g[base+1022]; tord[2]=ord_g[base+1022]; }
        }
    };
    auto pack1 = [](float f, int o) -> unsigned int {
        return ((unsigned int)o << 16) | (unsigned int)__half_as_ushort(__float2half(f));
    };
    auto commit = [&]() {
        unsigned int* pt = pk + (slot << 10);
        #pragma unroll
        for (int k = 0; k < 8; ++k) {
            int j = k * 128 + 4 * s;
            if (j < 1020) {
                pt[1+j+0]=pack1(pthr[k].x,pord[k].x); pt[1+j+1]=pack1(pthr[k].y,pord[k].y);
                pt[1+j+2]=pack1(pthr[k].z,pord[k].z); pt[1+j+3]=pack1(pthr[k].w,pord[k].w);
            } else { pt[1+1020]=pack1(tthr[0],tord[0]); pt[1+1021]=pack1(tthr[1],tord[1]);
                     pt[1+1022]=pack1(tthr[2],tord[2]); }
        }
    };
    prefetch(0);
    __builtin_amdgcn_sched_barrier(0);
    for (int g = 0; g < F_GROUPS; ++g) {
        __syncthreads();
        commit();
        __syncthreads();
        if (g + 1 < F_GROUPS) prefetch(g + 1);
        __builtin_amdgcn_sched_barrier(0);
        const int t = tb * F_TPB + g * F_TG + slot;
        const unsigned int* pkt = pk + (slot << 10);
        float minm = __builtin_inff();
        int sl = 1;
        unsigned int cur = pkt[1];
        #pragma unroll
        for (int d = 0; d < 10; ++d) {
            uint2 ch;
            if (d < 9) ch = *(const uint2*)(pkt + 2 * sl);
            float thv = __half2float(__ushort_as_half((unsigned short)(cur & 0xffffu)));
            int orv = (int)(cur >> 16);
            float feat = xs[(orv << 5) + s];
            float m = feat - thv;
            bool take = fabsf(m) < fabsf(minm);
            minm = take ? m : minm;
            int right = (m > 0.0f) ? 1 : 0;
            sl = 2 * sl + right;
            if (d < 9) cur = right ? ch.y : ch.x;
        }
        int leaf = sl - NL;
        float w = wts[(size_t)t * NL + leaf];
        int col = g * F_TG + slot;
        res[(s << 7) + ((col + s) & 127)] = fabsf(minm) * w;
    }
    __syncthreads();
    float* obase = out + (size_t)panel * F_SP * TT + (size_t)tb * F_TPB;
    #pragma unroll
    for (int k = 0; k < (F_SP * F_TPB) / 512; ++k) {
        int idx = k * 512 + tid, rr = idx >> 7, c = idx & 127;
        obase[(size_t)rr * TT + c] = res[(rr << 7) + ((c + rr) & 127)];
    }
}

// ===================== launch =====================
extern "C" void kernel_launch(void* const* d_in, const int* in_sizes, int n_in,
                              void* d_out, int out_size, void* d_ws, size_t ws_size,
                              hipStream_t stream) {
    const float* x    = (const float*)d_in[0];
    const float* thr  = (const float*)d_in[1];
    const int*   ordv = (const int*)d_in[2];
    const float* wts  = (const float*)d_in[3];
    float*       out  = (float*)d_out;

    const size_t pk_bytes   = (size_t)TT * 128 * 4;    // 2 MB
    const size_t g7_bytes   = (size_t)TT * 64 * 8;     // 2 MB
    const size_t g8_bytes   = (size_t)TT * 128 * 8;    // 4 MB
    const size_t tail_bytes = (size_t)TT * 256 * 16;   // 16 MB
    const size_t xt_bytes   = (size_t)CC * BB * 2;     // 4 MB

    if (d_ws && ws_size >= pk_bytes + g7_bytes + g8_bytes + tail_bytes + xt_bytes) {
        char* p = (char*)d_ws;
        unsigned*       pk_lo = (unsigned*)p;            p += pk_bytes;
        uint2*          g7    = (uint2*)p;               p += g7_bytes;
        uint2*          g8    = (uint2*)p;               p += g8_bytes;
        uint4*          tails = (uint4*)p;               p += tail_bytes;
        unsigned short* xt16  = (unsigned short*)p;
        pack_trees<<<TT, 256, 0, stream>>>(thr, ordv, wts, pk_lo, g7, g8, tails);
        dim3 gx(BB / 64, CC / 64);
        pack_x16<<<gx, 256, 0, stream>>>(x, xt16);
        (void)hipFuncSetAttribute((const void*)rhf_main,
                            hipFuncAttributeMaxDynamicSharedMemorySize, LDS_BYTES);
        rhf_main<<<2048, 1024, LDS_BYTES, stream>>>(pk_lo, g7, g8, tails, xt16, out);
    } else {
        (void)hipFuncSetAttribute((const void*)rhf_fallback,
                            hipFuncAttributeMaxDynamicSharedMemorySize, F_LDS);
        rhf_fallback<<<F_NPANELS * (TT / F_TPB), 512, F_LDS, stream>>>(x, thr, ordv, wts, out);
    }
}

// Round 17
// 111.317 us; speedup vs baseline: 2.3741x; 2.3741x over previous
//
#include <hip/hip_runtime.h>
#include <hip/hip_fp16.h>

#define BB 4096
#define CC 512
#define TT 4096
#define NN 1023
#define NL 1024

// ===================== pre-kernels (write d_ws) =====================

// node record: (ord*128) in high 16 bits (byte offset into a 64-sample xs row),
// f16(thr) in low 16. ord<512 -> ord*128 <= 65408 fits u16.
__device__ __forceinline__ unsigned pack_node(float th, int o) {
    return ((unsigned)o << 23) | (unsigned)__half_as_ushort(__float2half(th));
}

// pk_lo[t][j] j=0..127: slot j -> node j-1 (depths 0..6); slot 0 = 0.  (512B/tree)
// g7[t][j]  j=0..63 : depth-7 pair for depth-6 slot 64+j  : {tr[127+2j], tr[128+2j]}
// g8[t][j]  j=0..127: depth-8 pair for depth-7 slot 128+j : {tr[255+2j], tr[256+2j]}
// tails[t][i] i=0..255: depth-9 pair + leaf weights for depth-8 slot 256+i:
//            {tr[511+2i], tr[512+2i], w(4i,4i+1), w(4i+2,4i+3)}
__global__ __launch_bounds__(256)
void pack_trees(const float* __restrict__ thr, const int* __restrict__ ord,
                const float* __restrict__ wts, unsigned* __restrict__ pk_lo,
                uint2* __restrict__ g7, uint2* __restrict__ g8,
                uint4* __restrict__ tails) {
    int t = blockIdx.x, tid = threadIdx.x;
    const float* tr = thr + (size_t)t * NN;
    const int*   oo = ord + (size_t)t * NN;
    if (tid < 128) {
        unsigned* plo = pk_lo + ((size_t)t << 7);
        plo[tid] = (tid == 0) ? 0u : pack_node(tr[tid - 1], oo[tid - 1]);
    }
    if (tid < 64) {
        int j = tid;
        g7[((size_t)t << 6) + j] =
            make_uint2(pack_node(tr[127 + 2 * j], oo[127 + 2 * j]),
                       pack_node(tr[128 + 2 * j], oo[128 + 2 * j]));
    }
    if (tid < 128) {
        int j = tid;
        g8[((size_t)t << 7) + j] =
            make_uint2(pack_node(tr[255 + 2 * j], oo[255 + 2 * j]),
                       pack_node(tr[256 + 2 * j], oo[256 + 2 * j]));
    }
    int i = tid;
    int nL = 511 + 2 * i, nR = 512 + 2 * i;
    unsigned ndL = pack_node(tr[nL], oo[nL]);
    unsigned ndR = pack_node(tr[nR], oo[nR]);
    float4 w4 = *(const float4*)(wts + ((size_t)t << 10) + 4 * i);
    unsigned w01 = (unsigned)__half_as_ushort(__float2half(w4.x)) |
                   ((unsigned)__half_as_ushort(__float2half(w4.y)) << 16);
    unsigned w23 = (unsigned)__half_as_ushort(__float2half(w4.z)) |
                   ((unsigned)__half_as_ushort(__float2half(w4.w)) << 16);
    tails[((size_t)t << 8) + i] = make_uint4(ndL, ndR, w01, w23);
}

// xt16[c*4096 + b] = f16bits(x[b][c])
__global__ __launch_bounds__(256)
void pack_x16(const float* __restrict__ x, unsigned short* __restrict__ xt16) {
    __shared__ float tile[64][65];
    int tx = threadIdx.x & 63, ty = threadIdx.x >> 6;   // 64 x 4
    int b0 = blockIdx.x * 64;
    int c0 = blockIdx.y * 64;
    #pragma unroll
    for (int i = 0; i < 16; ++i) {
        int rr = i * 4 + ty;
        tile[rr][tx] = x[(size_t)(b0 + rr) * CC + c0 + tx];
    }
    __syncthreads();
    #pragma unroll
    for (int i = 0; i < 16; ++i) {
        int cr = i * 4 + ty;
        xt16[(size_t)(c0 + cr) * BB + b0 + tx] =
            __half_as_ushort(__float2half(tile[tx][cr]));
    }
}

// ===================== packed helpers =====================
typedef unsigned short u16x2 __attribute__((ext_vector_type(2)));

static __device__ __forceinline__ unsigned psub_f16x2(unsigned a, unsigned b) {
    __half2 ah, bh;
    __builtin_memcpy(&ah, &a, 4);
    __builtin_memcpy(&bh, &b, 4);
    __half2 r = ah - bh;
    unsigned u; __builtin_memcpy(&u, &r, 4); return u;
}
static __device__ __forceinline__ unsigned pmin_u16x2(unsigned a, unsigned b) {
    u16x2 av, bv;
    __builtin_memcpy(&av, &a, 4);
    __builtin_memcpy(&bv, &b, 4);
    u16x2 m = __builtin_elementwise_min(av, bv);
    unsigned u; __builtin_memcpy(&u, &m, 4); return u;
}
static __device__ __forceinline__ float f16lo(unsigned u) {
    return __half2float(__ushort_as_half((unsigned short)(u & 0xffffu)));
}
static __device__ __forceinline__ float f16hi(unsigned u) {
    return __half2float(__ushort_as_half((unsigned short)(u >> 16)));
}

// ===================== main kernel =====================
// grid 2048, XCD-swizzled. 1024 threads = 16 waves (4/SIMD), lane = sample,
// 8 chains/thread, SINGLE group of 128 trees (16 waves x 8). Depths 0..6 staged
// (128 slots, 512B/tree, wave-private). Levels 6,7 via 8B g7/g8 recs, level 8/9
// + weights via 16B tails (all exact, XCD-L2-resident, SGPR bases).
// LDS (exactly 160 KiB): xs16 64K @0 | trees 64K @64K | res f32[64][128] 32K @128K
#define LDS_BYTES 163840

typedef __attribute__((address_space(1))) const void gv_t;
typedef __attribute__((address_space(3))) void lv_t;

__global__ __launch_bounds__(1024, 1)
void rhf_main(const unsigned* __restrict__ pk_lo, const uint2* __restrict__ g7g,
              const uint2* __restrict__ g8g, const uint4* __restrict__ tails,
              const unsigned short* __restrict__ xt16, float* __restrict__ out) {
    extern __shared__ char smem[];
    const char*     xsb = (const char*)smem;            // xs16 byte base
    unsigned*       trl = (unsigned*)(smem + 65536);
    float*          res = (float*)(smem + 131072);

    const int tid  = threadIdx.x;
    const int lane = tid & 63;
    const int wv   = tid >> 6;          // 0..15
    const int bi   = blockIdx.x;
    const int tb    = ((bi & 7) << 2) + ((bi >> 3) >> 6);   // 0..31
    const int panel = (bi >> 3) & 63;                       // 0..63
    const int lane2 = lane << 1;        // byte offset of this sample in an xs row

    // ---- per-wave tree DMA: 8 trees x 512B = 4KB = 4 x (64 lanes x 16B) ----
    {
        const char* s = (const char*)pk_lo + ((size_t)(tb * 128 + wv * 8) << 9) + lane * 16;
        char* d = (char*)trl + wv * 4096 + lane * 16;
        #pragma unroll
        for (int q = 0; q < 4; ++q)
            __builtin_amdgcn_global_load_lds((gv_t*)(s + q * 1024),
                                             (lv_t*)(d + q * 1024), 16, 0, 0);
    }

    // ---- stage xs16 (coalesced 16B, linear LDS writes) ----
    {
        const unsigned short* src = xt16 + (size_t)panel * 64;
        #pragma unroll
        for (int k = 0; k < 4; ++k) {
            int i4 = k * 1024 + tid;
            int c  = i4 >> 3;
            int o8 = (i4 & 7) << 3;
            uint4 v = *(const uint4*)(src + (size_t)c * BB + o8);
            *(uint4*)((char*)smem + ((size_t)i4 << 4)) = v;
        }
    }
    __syncthreads();   // xs16 visible; tree DMA drained (barrier drains vmcnt)

    const int t0 = tb * 128 + wv * 8;           // wave-uniform first tree
    const unsigned* pkw = trl + wv * 1024;      // this wave's 8 x 128 slots

    // packed eval for chains (a,b): updates amin, returns branch bits
    auto evalpair = [&](unsigned nd_a, unsigned nd_b, unsigned& amin,
                        unsigned& r_a, unsigned& r_b) {
        unsigned thv2 = (nd_a & 0xffffu) | (nd_b << 16);
        unsigned short fa = *(const unsigned short*)(xsb + (nd_a >> 16) + lane2);
        unsigned short fb = *(const unsigned short*)(xsb + (nd_b >> 16) + lane2);
        unsigned feat2 = (unsigned)fa | ((unsigned)fb << 16);
        unsigned mb = psub_f16x2(feat2, thv2);
        amin = pmin_u16x2(amin, mb & 0x7fff7fffu);
        r_a = ((mb >> 15) & 1u) ^ 1u;
        r_b = (mb >> 31) ^ 1u;
    };

    unsigned amin[4];
    int      sl[8];
    unsigned nd[8];
    unsigned r[8];
    #pragma unroll
    for (int p = 0; p < 4; ++p) amin[p] = 0x7c007c00u;
    #pragma unroll
    for (int c = 0; c < 8; ++c) { sl[c] = 1; nd[c] = pkw[c * 128 + 1]; }

    // ---- levels 0..5 (children from LDS) ----
    #pragma unroll
    for (int d = 0; d < 6; ++d) {
        uint2 ch[8];
        #pragma unroll
        for (int c = 0; c < 8; ++c)
            ch[c] = *(const uint2*)(pkw + c * 128 + 2 * sl[c]);
        #pragma unroll
        for (int p = 0; p < 4; ++p)
            evalpair(nd[2 * p], nd[2 * p + 1], amin[p], r[2 * p], r[2 * p + 1]);
        #pragma unroll
        for (int c = 0; c < 8; ++c) {
            sl[c] = 2 * sl[c] + (int)r[c];
            nd[c] = r[c] ? ch[c].y : ch[c].x;
        }
    }

    // ---- level 6: depth-7 pairs from g7 (8B, L2) ----
    {
        uint2 q[8];
        #pragma unroll
        for (int c = 0; c < 8; ++c)
            q[c] = g7g[((size_t)(t0 + c) << 6) + (sl[c] - 64)];
        #pragma unroll
        for (int p = 0; p < 4; ++p)
            evalpair(nd[2 * p], nd[2 * p + 1], amin[p], r[2 * p], r[2 * p + 1]);
        #pragma unroll
        for (int c = 0; c < 8; ++c) {
            sl[c] = 2 * sl[c] + (int)r[c];
            nd[c] = r[c] ? q[c].y : q[c].x;
        }
    }

    // ---- level 7: depth-8 pairs from g8 (8B, L2) ----
    {
        uint2 q[8];
        #pragma unroll
        for (int c = 0; c < 8; ++c)
            q[c] = g8g[((size_t)(t0 + c) << 7) + (sl[c] - 128)];
        #pragma unroll
        for (int p = 0; p < 4; ++p)
            evalpair(nd[2 * p], nd[2 * p + 1], amin[p], r[2 * p], r[2 * p + 1]);
        #pragma unroll
        for (int c = 0; c < 8; ++c) {
            sl[c] = 2 * sl[c] + (int)r[c];
            nd[c] = r[c] ? q[c].y : q[c].x;
        }
    }

    // ---- level 8: tails (16B, L2) -> depth-9 node + weight word ----
    unsigned wsel[8];
    {
        uint4 e[8];
        #pragma unroll
        for (int c = 0; c < 8; ++c)
            e[c] = tails[((size_t)(t0 + c) << 8) + (sl[c] - 256)];
        #pragma unroll
        for (int p = 0; p < 4; ++p)
            evalpair(nd[2 * p], nd[2 * p + 1], amin[p], r[2 * p], r[2 * p + 1]);
        #pragma unroll
        for (int c = 0; c < 8; ++c) {
            nd[c]   = r[c] ? e[c].y : e[c].x;
            wsel[c] = r[c] ? e[c].w : e[c].z;
        }
    }

    // ---- level 9 + weight, write res ----
    {
        #pragma unroll
        for (int p = 0; p < 4; ++p)
            evalpair(nd[2 * p], nd[2 * p + 1], amin[p], r[2 * p], r[2 * p + 1]);
        #pragma unroll
        for (int c = 0; c < 8; ++c) {
            unsigned short wb = (unsigned short)(r[c] ? (wsel[c] >> 16) : (wsel[c] & 0xffffu));
            float am = (c & 1) ? f16hi(amin[c >> 1]) : f16lo(amin[c >> 1]);
            float o  = am * __half2float(__ushort_as_half(wb));
            int col = wv * 8 + c;
            res[(lane << 7) + ((col + lane) & 127)] = o;
        }
    }
    __syncthreads();

    // ---- coalesced output ----
    float* obase = out + (size_t)(tb * 128);
    #pragma unroll
    for (int k = 0; k < 8; ++k) {
        int idx = k * 1024 + tid;
        int rr = idx >> 7, cc = idx & 127;
        float v = res[(rr << 7) + ((cc + rr) & 127)];
        obase[((size_t)panel * 64 + rr) * TT + cc] = v;
    }
}

// ===================== fallback (round-4, proven 541us) =====================
#define F_SP 32
#define F_TG 16
#define F_GROUPS 8
#define F_TPB (F_TG * F_GROUPS)
#define F_NPANELS (BB / F_SP)
#define F_LDS 147456

__global__ __launch_bounds__(512, 1)
void rhf_fallback(const float* __restrict__ x, const float* __restrict__ thr_g,
                  const int* __restrict__ ord_g, const float* __restrict__ wts,
                  float* __restrict__ out) {
    extern __shared__ char smem[];
    float*        xs  = (float*)(smem);
    unsigned int* pk  = (unsigned int*)(smem + 65536);
    float*        res = (float*)(smem + 131072);
    const int tid = threadIdx.x, s = tid & 31, slot = tid >> 5;
    const int panel = blockIdx.x & (F_NPANELS - 1), tb = blockIdx.x >> 7;
    const float* xbase = x + (size_t)panel * F_SP * CC;
    #pragma unroll
    for (int k = 0; k < (F_SP * CC) / 512; ++k) {
        int idx = k * 512 + tid, r = idx >> 9, c = idx & 511;
        xs[(c << 5) + r] = xbase[r * CC + c];
    }
    float4 pthr[8]; int4 pord[8]; float tthr[3]; int tord[3];
    auto prefetch = [&](int g) {
        const size_t base = (size_t)(tb * F_TPB + g * F_TG + slot) * NN;
        #pragma unroll
        for (int k = 0; k < 8; ++k) {
            int j = k * 128 + 4 * s;
            if (j < 1020) { pthr[k] = *(const float4*)(thr_g + base + j);
                            pord[k] = *(const int4*)(ord_g + base + j); }
            else { tthr[0]=thr_g[base+1020]; tord[0]=ord_g[base+1020];
                   tthr[1]=thr_g[base+1021]; tord[1]=ord_g[base+1021];
                   tthr[2]=thr_g[base+1022]; tord[2]=ord_g[base+1022]; }
        }
    };
    auto pack1 = [](float f, int o) -> unsigned int {
        return ((unsigned int)o << 16) | (unsigned int)__half_as_ushort(__float2half(f));
    };
    auto commit = [&]() {
        unsigned int* pt = pk + (slot << 10);
        #pragma unroll
        for (int k = 0; k < 8; ++k) {
            int j = k * 128 + 4 * s;
            if (j < 1020) {
                pt[1+j+0]=pack1(pthr[k].x,pord[k].x); pt[1+j+1]=pack1(pthr[k].y,pord[k].y);
                pt[1+j+2]=pack1(pthr[k].z,pord[k].z); pt[1+j+3]=pack1(pthr[k].w,pord[k].w);
            } else { pt[1+1020]=pack1(tthr[0],tord[0]); pt[1+1021]=pack1(tthr[1],tord[1]);
                     pt[1+1022]=pack1(tthr[2],tord[2]); }
        }
    };
    prefetch(0);
    __builtin_amdgcn_sched_barrier(0);
    for (int g = 0; g < F_GROUPS; ++g) {
        __syncthreads();
        commit();
        __syncthreads();
        if (g + 1 < F_GROUPS) prefetch(g + 1);
        __builtin_amdgcn_sched_barrier(0);
        const int t = tb * F_TPB + g * F_TG + slot;
        const unsigned int* pkt = pk + (slot << 10);
        float minm = __builtin_inff();
        int sl = 1;
        unsigned int cur = pkt[1];
        #pragma unroll
        for (int d = 0; d < 10; ++d) {
            uint2 ch;
            if (d < 9) ch = *(const uint2*)(pkt + 2 * sl);
            float thv = __half2float(__ushort_as_half((unsigned short)(cur & 0xffffu)));
            int orv = (int)(cur >> 16);
            float feat = xs[(orv << 5) + s];
            float m = feat - thv;
            bool take = fabsf(m) < fabsf(minm);
            minm = take ? m : minm;
            int right = (m > 0.0f) ? 1 : 0;
            sl = 2 * sl + right;
            if (d < 9) cur = right ? ch.y : ch.x;
        }
        int leaf = sl - NL;
        float w = wts[(size_t)t * NL + leaf];
        int col = g * F_TG + slot;
        res[(s << 7) + ((col + s) & 127)] = fabsf(minm) * w;
    }
    __syncthreads();
    float* obase = out + (size_t)panel * F_SP * TT + (size_t)tb * F_TPB;
    #pragma unroll
    for (int k = 0; k < (F_SP * F_TPB) / 512; ++k) {
        int idx = k * 512 + tid, rr = idx >> 7, c = idx & 127;
        obase[(size_t)rr * TT + c] = res[(rr << 7) + ((c + rr) & 127)];
    }
}

// ===================== launch =====================
extern "C" void kernel_launch(void* const* d_in, const int* in_sizes, int n_in,
                              void* d_out, int out_size, void* d_ws, size_t ws_size,
                              hipStream_t stream) {
    const float* x    = (const float*)d_in[0];
    const float* thr  = (const float*)d_in[1];
    const int*   ordv = (const int*)d_in[2];
    const float* wts  = (const float*)d_in[3];
    float*       out  = (float*)d_out;

    const size_t pk_bytes   = (size_t)TT * 128 * 4;    // 2 MB
    const size_t g7_bytes   = (size_t)TT * 64 * 8;     // 2 MB
    const size_t g8_bytes   = (size_t)TT * 128 * 8;    // 4 MB
    const size_t tail_bytes = (size_t)TT * 256 * 16;   // 16 MB
    const size_t xt_bytes   = (size_t)CC * BB * 2;     // 4 MB

    if (d_ws && ws_size >= pk_bytes + g7_bytes + g8_bytes + tail_bytes + xt_bytes) {
        char* p = (char*)d_ws;
        unsigned*       pk_lo = (unsigned*)p;            p += pk_bytes;
        uint2*          g7    = (uint2*)p;               p += g7_bytes;
        uint2*          g8    = (uint2*)p;               p += g8_bytes;
        uint4*          tails = (uint4*)p;               p += tail_bytes;
        unsigned short* xt16  = (unsigned short*)p;
        pack_trees<<<TT, 256, 0, stream>>>(thr, ordv, wts, pk_lo, g7, g8, tails);
        dim3 gx(BB / 64, CC / 64);
        pack_x16<<<gx, 256, 0, stream>>>(x, xt16);
        (void)hipFuncSetAttribute((const void*)rhf_main,
                            hipFuncAttributeMaxDynamicSharedMemorySize, LDS_BYTES);
        rhf_main<<<2048, 1024, LDS_BYTES, stream>>>(pk_lo, g7, g8, tails, xt16, out);
    } else {
        (void)hipFuncSetAttribute((const void*)rhf_fallback,
                            hipFuncAttributeMaxDynamicSharedMemorySize, F_LDS);
        rhf_fallback<<<F_NPANELS * (TT / F_TPB), 512, F_LDS, stream>>>(x, thr, ordv, wts, out);
    }
}